// Round 1
// 477.391 us; speedup vs baseline: 1.0685x; 1.0685x over previous
//
#include <hip/hip_runtime.h>
#include <hip/hip_bf16.h>

#define B_  2
#define S_  2048
#define D_  1024
#define H_  16
#define HD_ 64
#define M_  (B_ * S_)   // 4096

typedef unsigned short u16;
typedef __attribute__((ext_vector_type(8))) short short8;
typedef __attribute__((ext_vector_type(4))) float f32x4;

#define MFMA16(a, b, c) __builtin_amdgcn_mfma_f32_16x16x32_bf16(a, b, c, 0, 0, 0)

__device__ __forceinline__ u16 f2bf(float f) {
    union { float f; unsigned u; } v; v.f = f;
    unsigned r = v.u + 0x7FFFu + ((v.u >> 16) & 1u);  // RNE
    return (u16)(r >> 16);
}

__device__ __forceinline__ void gl_lds16(const void* g, void* lds) {
    __builtin_amdgcn_global_load_lds(
        (const __attribute__((address_space(1))) unsigned int*)g,
        (__attribute__((address_space(3))) unsigned int*)lds, 16, 0, 0);
}

// ---------------------------------------------------------------------------
// Pre-pass 1: fp32 -> bf16 (X)
// ---------------------------------------------------------------------------
__global__ __launch_bounds__(256) void cvt_bf16(const float* __restrict__ x,
                                                u16* __restrict__ y) {
    const int i = (blockIdx.x * 256 + threadIdx.x) * 4;
    const float4 v = *(const float4*)(x + i);
    ushort4 o;
    o.x = f2bf(v.x); o.y = f2bf(v.y); o.z = f2bf(v.z); o.w = f2bf(v.w);
    *(ushort4*)(y + i) = o;
}

// ---------------------------------------------------------------------------
// Pre-pass 2: W[K,N] fp32 -> Wt[N,K] bf16, 4 weights via blockIdx.z
// ---------------------------------------------------------------------------
__global__ __launch_bounds__(256) void wt_trans(
    const float* __restrict__ w0, const float* __restrict__ w1,
    const float* __restrict__ w2, const float* __restrict__ w3,
    u16* __restrict__ t0, u16* __restrict__ t1,
    u16* __restrict__ t2, u16* __restrict__ t3) {
    const float* W; u16* T;
    switch (blockIdx.z) {
        case 0: W = w0; T = t0; break;
        case 1: W = w1; T = t1; break;
        case 2: W = w2; T = t2; break;
        default: W = w3; T = t3; break;
    }
    __shared__ float t[32][33];
    const int tid = threadIdx.x;
    const int kt = blockIdx.x, nt = blockIdx.y;
    const int r = tid >> 3, c4 = (tid & 7) * 4;
    const float4 v = *(const float4*)&W[(size_t)(kt * 32 + r) * D_ + nt * 32 + c4];
    t[c4 + 0][r] = v.x; t[c4 + 1][r] = v.y; t[c4 + 2][r] = v.z; t[c4 + 3][r] = v.w;
    __syncthreads();
    ushort4 o;
    o.x = f2bf(t[r][c4 + 0]); o.y = f2bf(t[r][c4 + 1]);
    o.z = f2bf(t[r][c4 + 2]); o.w = f2bf(t[r][c4 + 3]);
    *(ushort4*)&T[(size_t)(nt * 32 + r) * D_ + kt * 32 + c4] = o;
}

// ---------------------------------------------------------------------------
// Pre-pass 3: V [B,H,S,HD] bf16 -> VT [B,H,HD,S] bf16 (64x64 LDS tiles)
// ---------------------------------------------------------------------------
__global__ __launch_bounds__(256) void v_trans(const u16* __restrict__ V,
                                               u16* __restrict__ VT) {
    __shared__ u16 t[64][72];
    const int bh = blockIdx.x, s0 = blockIdx.y * 64;
    const int tid = threadIdx.x;
    const int ss = tid >> 2, cq = tid & 3;
    const u16* src = V + ((size_t)bh * S_ + s0 + ss) * HD_ + cq * 16;
    u16 buf[16];
    *(uint4*)&buf[0] = *(const uint4*)&src[0];
    *(uint4*)&buf[8] = *(const uint4*)&src[8];
#pragma unroll
    for (int j = 0; j < 16; ++j) t[cq * 16 + j][ss] = buf[j];
    __syncthreads();
    const int dd = tid >> 2;
    u16 ob[16];
#pragma unroll
    for (int j = 0; j < 16; ++j) ob[j] = t[dd][cq * 16 + j];
    u16* dst = VT + ((size_t)bh * HD_ + dd) * S_ + s0 + cq * 16;
    *(uint4*)&dst[0] = *(uint4*)&ob[0];
    *(uint4*)&dst[8] = *(uint4*)&ob[8];
}

// ---------------------------------------------------------------------------
// bf16 MFMA GEMM, double-buffered single-barrier K-loop.
// C[M,N] = A[M,K] @ Bt[N,K]^T + bias. 128x128 tile, BK=32, 256 thr (2x2 waves).
// LDS: A0 | A1 | B0 | B1 (8 KB each) = 32 KB.
// mode 1: scatter bf16 to [B,H,S,HD], out/bias by n>>10 (fused QKV, grid.y=24).
// mode 0: fp32 row-major [M,1024].
// ---------------------------------------------------------------------------
__global__ __launch_bounds__(256, 3) void gemm_bt_bf16(
    const u16* __restrict__ A, const u16* __restrict__ Bt,
    const float* __restrict__ bi0, const float* __restrict__ bi1, const float* __restrict__ bi2,
    void* __restrict__ o0, void* __restrict__ o1, void* __restrict__ o2,
    int mode) {
    __shared__ __align__(16) char smem[32768];

    const int tid = threadIdx.x;
    const int wave = tid >> 6, lane = tid & 63;
    const int quad = lane >> 4, l15 = lane & 15;
    const int wm = wave >> 1, wn = wave & 1;
    const int bm = blockIdx.x * 128, bn = blockIdx.y * 128;

    const int sel = bn >> 10;
    const float* bias = (sel == 0) ? bi0 : (sel == 1) ? bi1 : bi2;
    void* outp = (sel == 0) ? o0 : (sel == 1) ? o1 : o2;

    f32x4 acc[4][4];
#pragma unroll
    for (int i = 0; i < 4; ++i)
#pragma unroll
        for (int j = 0; j < 4; ++j) acc[i][j] = (f32x4)0.f;

    // chunk assignment for staging: c in 0..511, row=c>>2, e=c&3
    const int c0 = wave * 128 + lane;          // base chunk (i=0); i adds 64
    // prologue: stage k0=0 into buf0
#pragma unroll
    for (int i = 0; i < 2; ++i) {
        const int c = c0 + i * 64;
        const int row = c >> 2, e = c & 3;
        gl_lds16(A  + (size_t)(bm + row) * D_ + e * 8,
                 smem + (wave * 2 + i) * 1024);
        gl_lds16(Bt + (size_t)(bn + row) * D_ + e * 8,
                 smem + 16384 + (wave * 2 + i) * 1024);
    }
    __syncthreads();

    for (int it = 0; it < 32; ++it) {
        const int cur = it & 1;
        // stage next tile into the other buffer (DMA overlaps compute below)
        if (it < 31) {
            const int k0n = (it + 1) * 32;
            const int nb = cur ^ 1;
#pragma unroll
            for (int i = 0; i < 2; ++i) {
                const int c = c0 + i * 64;
                const int row = c >> 2, e = c & 3;
                gl_lds16(A  + (size_t)(bm + row) * D_ + k0n + e * 8,
                         smem + nb * 8192 + (wave * 2 + i) * 1024);
                gl_lds16(Bt + (size_t)(bn + row) * D_ + k0n + e * 8,
                         smem + 16384 + nb * 8192 + (wave * 2 + i) * 1024);
            }
        }

        short8 aF[4], bF[4];
#pragma unroll
        for (int mt = 0; mt < 4; ++mt)
            aF[mt] = *(const short8*)(smem + cur * 8192 +
                     ((wm * 64 + mt * 16 + l15) * 32 + quad * 8) * 2);
#pragma unroll
        for (int nt = 0; nt < 4; ++nt)
            bF[nt] = *(const short8*)(smem + 16384 + cur * 8192 +
                     ((wn * 64 + nt * 16 + l15) * 32 + quad * 8) * 2);
#pragma unroll
        for (int mt = 0; mt < 4; ++mt)
#pragma unroll
            for (int nt = 0; nt < 4; ++nt)
                acc[mt][nt] = MFMA16(aF[mt], bF[nt], acc[mt][nt]);

        __syncthreads();   // next-tile DMA complete + all waves done with cur
    }

    float bv[4];
#pragma unroll
    for (int nt = 0; nt < 4; ++nt)
        bv[nt] = bias[(bn & 1023) + wn * 64 + nt * 16 + l15];

    if (mode == 1) {
        u16* ob = (u16*)outp;
#pragma unroll
        for (int mt = 0; mt < 4; ++mt)
#pragma unroll
            for (int nt = 0; nt < 4; ++nt)
#pragma unroll
                for (int r = 0; r < 4; ++r) {
                    const int m = bm + wm * 64 + mt * 16 + quad * 4 + r;
                    const int n = (bn & 1023) + wn * 64 + nt * 16 + l15;
                    const int bb = m >> 11, ss = m & (S_ - 1);
                    const int hh = n >> 6,  dd = n & (HD_ - 1);
                    ob[(((size_t)bb * H_ + hh) * S_ + ss) * HD_ + dd] =
                        f2bf(acc[mt][nt][r] + bv[nt]);
                }
    } else {
        float* of = (float*)outp;
#pragma unroll
        for (int mt = 0; mt < 4; ++mt)
#pragma unroll
            for (int nt = 0; nt < 4; ++nt)
#pragma unroll
                for (int r = 0; r < 4; ++r) {
                    const int m = bm + wm * 64 + mt * 16 + quad * 4 + r;
                    const int n = bn + wn * 64 + nt * 16 + l15;
                    of[(size_t)m * D_ + n] = acc[mt][nt][r] + bv[nt];
                }
    }
}

// ---------------------------------------------------------------------------
// MFMA flash attention, TQ=64, both batches fused per block (pb read ONCE).
// Block = 256 thr (4 waves x 16 q-rows), grid = (S/64, H) = 512 blocks.
// LDS: 8K (Q_b0 -> Ps) | 4x8K K (buf x batch) | 4x8K V = 72 KB -> 2 blocks/CU
// (512 blocks = exactly one full dispatch wave at 2/CU).
// Q_b1 is staged into K slot (buf1,b1) and hoisted to registers before kt=0's
// prefetch DMA overwrites it (in-wave ds_read -> global_load_lds ordering).
// position_bias register loads are pipelined one full K-tile ahead to hide
// ~900-cyc HBM latency at the reduced occupancy (2 waves/SIMD).
// ---------------------------------------------------------------------------
#define PS_OFF   0        // Q(b0), reused as Ps after register hoist
#define AK2_OFF  8192     // + ((buf*2)+b)*8192, 4 slots
#define AV2_OFF  40960    // + ((buf*2)+b)*8192, 4 slots
#define Q1_STAGE 32768    // = K slot (buf1,b1): free until kt=0 prefetch

__global__ __launch_bounds__(256, 2) void attn_mfma(
    const u16* __restrict__ Qg, const u16* __restrict__ Kg, const u16* __restrict__ VTg,
    const float* __restrict__ pb, const float* __restrict__ mask,
    u16* __restrict__ Cb) {
    __shared__ __align__(16) char smem[73728];
    u16* PsU = (u16*)(smem + PS_OFF);

    const int tid = threadIdx.x;
    const int wave = tid >> 6, lane = tid & 63;
    const int quad = lane >> 4, l15 = lane & 15;

    const int qblk = blockIdx.x;
    const int h = blockIdx.y;
    const int q0 = qblk * 64;

    const u16* Qb0 = Qg  + (size_t)h        * (S_ * HD_);
    const u16* Qb1 = Qg  + (size_t)(H_ + h) * (S_ * HD_);
    const u16* Kb0 = Kg  + (size_t)h        * (S_ * HD_);
    const u16* Kb1 = Kg  + (size_t)(H_ + h) * (S_ * HD_);
    const u16* VT0 = VTg + (size_t)h        * (HD_ * S_);   // [HD][S]
    const u16* VT1 = VTg + (size_t)(H_ + h) * (HD_ * S_);

    // ---- prologue: stage Q(b0,b1) + K/V tile 0 (buf 0, both batches) ----
#pragma unroll
    for (int i = 0; i < 2; ++i) {
        const int c = (wave * 2 + i) * 64 + lane;  // 0..511
        const int row = c >> 3, e = c & 7, dc = e ^ (row & 7);
        const int off = (wave * 2 + i) * 1024;
        gl_lds16(Qb0 + (size_t)(q0 + row) * HD_ + dc * 8, smem + PS_OFF + off);
        gl_lds16(Qb1 + (size_t)(q0 + row) * HD_ + dc * 8, smem + Q1_STAGE + off);
        gl_lds16(Kb0 + (size_t)row * HD_ + dc * 8, smem + AK2_OFF + 0 * 8192 + off);
        gl_lds16(Kb1 + (size_t)row * HD_ + dc * 8, smem + AK2_OFF + 1 * 8192 + off);
        gl_lds16(VT0 + (size_t)row * S_ + dc * 8,  smem + AV2_OFF + 0 * 8192 + off);
        gl_lds16(VT1 + (size_t)row * S_ + dc * 8,  smem + AV2_OFF + 1 * 8192 + off);
    }
    __syncthreads();

    // hoist Q fragments for both batches (own-wave rows only)
    short8 aQ[2][2];
#pragma unroll
    for (int kc = 0; kc < 2; ++kc) {
        const int q = wave * 16 + l15;
        const int dc = kc * 4 + quad;
        const int boff = (q * 8 + (dc ^ (q & 7))) * 16;
        aQ[0][kc] = *(const short8*)(smem + PS_OFF + boff);
        aQ[1][kc] = *(const short8*)(smem + Q1_STAGE + boff);
    }

    // Ps addressing (kchunk-major): write base for this thread
    u16* Pw = PsU + (l15 >> 3) * 512 + (wave * 16 + quad * 4) * 8 + (l15 & 7);

    f32x4 O[2][4];
    float lst[2][4];
#pragma unroll
    for (int bb = 0; bb < 2; ++bb)
#pragma unroll
        for (int nt = 0; nt < 4; ++nt) { O[bb][nt] = (f32x4)0.f; lst[bb][nt] = 0.f; }

    // pipelined bias/mask registers for kt=0
    float pbc[4][4], mkc[2][4];
#pragma unroll
    for (int nt = 0; nt < 4; ++nt) {
        mkc[0][nt] = mask[nt * 16 + l15];
        mkc[1][nt] = mask[S_ + nt * 16 + l15];
    }
#pragma unroll
    for (int r = 0; r < 4; ++r) {
        const int qg = q0 + wave * 16 + quad * 4 + r;
        const float* rowp = pb + ((size_t)h * S_ + qg) * S_;
#pragma unroll
        for (int nt = 0; nt < 4; ++nt)
            pbc[r][nt] = __builtin_nontemporal_load(rowp + nt * 16 + l15);
    }

    for (int kt = 0; kt < S_ / 64; ++kt) {
        const int k0 = kt * 64;
        const int cur = kt & 1;
        float pbn[4][4], mkn[2][4];

        if (kt < S_ / 64 - 1) {
            const int nb = cur ^ 1;
            const int k0n = k0 + 64;
            // stage next K/V tiles (both batches) into the other buffer
#pragma unroll
            for (int i = 0; i < 2; ++i) {
                const int c = (wave * 2 + i) * 64 + lane;
                const int row = c >> 3, e = c & 7, dc = e ^ (row & 7);
                const int off = (wave * 2 + i) * 1024;
                gl_lds16(Kb0 + (size_t)(k0n + row) * HD_ + dc * 8,
                         smem + AK2_OFF + (nb * 2 + 0) * 8192 + off);
                gl_lds16(Kb1 + (size_t)(k0n + row) * HD_ + dc * 8,
                         smem + AK2_OFF + (nb * 2 + 1) * 8192 + off);
                gl_lds16(VT0 + (size_t)row * S_ + k0n + dc * 8,
                         smem + AV2_OFF + (nb * 2 + 0) * 8192 + off);
                gl_lds16(VT1 + (size_t)row * S_ + k0n + dc * 8,
                         smem + AV2_OFF + (nb * 2 + 1) * 8192 + off);
            }
            // next-tile bias/mask into registers (full kt of compute to hide)
#pragma unroll
            for (int nt = 0; nt < 4; ++nt) {
                mkn[0][nt] = mask[k0n + nt * 16 + l15];
                mkn[1][nt] = mask[S_ + k0n + nt * 16 + l15];
            }
#pragma unroll
            for (int r = 0; r < 4; ++r) {
                const int qg = q0 + wave * 16 + quad * 4 + r;
                const float* rowp = pb + ((size_t)h * S_ + qg) * S_ + k0n;
#pragma unroll
                for (int nt = 0; nt < 4; ++nt)
                    pbn[r][nt] = __builtin_nontemporal_load(rowp + nt * 16 + l15);
            }
        }

#pragma unroll
        for (int bb = 0; bb < 2; ++bb) {
            const int koff = AK2_OFF + (cur * 2 + bb) * 8192;
            const int voff = AV2_OFF + (cur * 2 + bb) * 8192;

            // ---- QK^T on buf[cur][bb] ----
            f32x4 sc[4];
#pragma unroll
            for (int nt = 0; nt < 4; ++nt) sc[nt] = (f32x4)0.f;
#pragma unroll
            for (int nt = 0; nt < 4; ++nt)
#pragma unroll
                for (int kc = 0; kc < 2; ++kc) {
                    const int kk = nt * 16 + l15;
                    const int dc = kc * 4 + quad;
                    const short8 bK = *(const short8*)(smem + koff +
                                       (kk * 8 + (dc ^ (kk & 7))) * 16);
                    sc[nt] = MFMA16(aQ[bb][kc], bK, sc[nt]);
                }

            // ---- no-max softmax: p = exp(s), per-lane partial row sums ----
#pragma unroll
            for (int r = 0; r < 4; ++r) {
                const float s0 = fmaf(sc[0][r], 0.125f, pbc[r][0] + mkc[bb][0]);
                const float s1 = fmaf(sc[1][r], 0.125f, pbc[r][1] + mkc[bb][1]);
                const float s2 = fmaf(sc[2][r], 0.125f, pbc[r][2] + mkc[bb][2]);
                const float s3 = fmaf(sc[3][r], 0.125f, pbc[r][3] + mkc[bb][3]);
                const float p0 = __expf(s0), p1 = __expf(s1);
                const float p2 = __expf(s2), p3 = __expf(s3);
                lst[bb][r] += (p0 + p1) + (p2 + p3);
                Pw[0 * 1024 + r * 8] = f2bf(p0);
                Pw[1 * 1024 + r * 8] = f2bf(p1);
                Pw[2 * 1024 + r * 8] = f2bf(p2);
                Pw[3 * 1024 + r * 8] = f2bf(p3);
            }

            // ---- PV on buf[cur][bb] (Ps is wave-private; in-wave DS order) ----
            short8 aP[2];
#pragma unroll
            for (int kc = 0; kc < 2; ++kc)
                aP[kc] = *(const short8*)(PsU + (kc * 4 + quad) * 512 +
                                          (wave * 16 + l15) * 8);
#pragma unroll
            for (int nt = 0; nt < 4; ++nt)
#pragma unroll
                for (int kc = 0; kc < 2; ++kc) {
                    const int d = nt * 16 + l15;
                    const int dc = kc * 4 + quad;
                    const short8 bV = *(const short8*)(smem + voff +
                                       (d * 8 + (dc ^ (d & 7))) * 16);
                    O[bb][nt] = MFMA16(aP[kc], bV, O[bb][nt]);
                }
        }

        if (kt < S_ / 64 - 1) {
#pragma unroll
            for (int r = 0; r < 4; ++r)
#pragma unroll
                for (int nt = 0; nt < 4; ++nt) pbc[r][nt] = pbn[r][nt];
#pragma unroll
            for (int nt = 0; nt < 4; ++nt) {
                mkc[0][nt] = mkn[0][nt]; mkc[1][nt] = mkn[1][nt];
            }
        }
        __syncthreads();   // next-tile DMA complete + all waves done with cur
    }

    // ---- epilogue: reduce l across the 16 col-lanes, write ctx bf16 ----
#pragma unroll
    for (int bb = 0; bb < 2; ++bb)
#pragma unroll
        for (int r = 0; r < 4; ++r) {
            float l = lst[bb][r];
#pragma unroll
            for (int off = 1; off < 16; off <<= 1)
                l += __shfl_xor(l, off, 64);
            const float inv = 1.f / l;
            const int s = q0 + wave * 16 + quad * 4 + r;
            u16* dst = Cb + ((size_t)bb * S_ + s) * D_ + h * HD_;
#pragma unroll
            for (int nt = 0; nt < 4; ++nt)
                dst[nt * 16 + l15] = f2bf(O[bb][nt][r] * inv);
        }
}

// ---------------------------------------------------------------------------
extern "C" void kernel_launch(void* const* d_in, const int* in_sizes, int n_in,
                              void* d_out, int out_size, void* d_ws, size_t ws_size,
                              hipStream_t stream) {
    const float* X    = (const float*)d_in[0];
    const float* mask = (const float*)d_in[1];
    const float* pb   = (const float*)d_in[2];
    const float* Wq   = (const float*)d_in[3];
    const float* bq   = (const float*)d_in[4];
    const float* Wk   = (const float*)d_in[5];
    const float* bk   = (const float*)d_in[6];
    const float* Wv   = (const float*)d_in[7];
    const float* bv   = (const float*)d_in[8];
    const float* Wo   = (const float*)d_in[9];
    const float* bo   = (const float*)d_in[10];
    float* out = (float*)d_out;

    // workspace (bf16 elems): 56 MB total
    u16* Xb    = (u16*)d_ws;                     // [4096,1024]       8 MB
    u16* WtQKV = Xb    + (size_t)M_ * D_;        // [3072,1024]       6 MB
    u16* Wto   = WtQKV + (size_t)3 * D_ * D_;    // [1024,1024]       2 MB
    u16* Qw    = Wto   + (size_t)D_ * D_;        // [B,H,S,HD]        8 MB
    u16* Kw    = Qw    + (size_t)M_ * D_;        //                   8 MB
    u16* Vw    = Kw    + (size_t)M_ * D_;        //                   8 MB
    u16* Cb    = Vw    + (size_t)M_ * D_;        // [B,S,D]           8 MB
    u16* VTw   = Cb    + (size_t)M_ * D_;        // [B,H,HD,S]        8 MB

    cvt_bf16<<<(M_ * D_) / (256 * 4), 256, 0, stream>>>(X, Xb);
    wt_trans<<<dim3(32, 32, 4), 256, 0, stream>>>(
        Wq, Wk, Wv, Wo, WtQKV, WtQKV + (size_t)D_ * D_, WtQKV + (size_t)2 * D_ * D_, Wto);

    // fused QKV: N = 3072
    gemm_bt_bf16<<<dim3(M_ / 128, 3 * D_ / 128), 256, 0, stream>>>(
        Xb, WtQKV, bq, bk, bv, Qw, Kw, Vw, 1);

    v_trans<<<dim3(B_ * H_, S_ / 64), 256, 0, stream>>>(Vw, VTw);

    // both batches fused per block: pb panel read once
    attn_mfma<<<dim3(S_ / 64, H_), 256, 0, stream>>>(Qw, Kw, VTw, pb, mask, Cb);

    gemm_bt_bf16<<<dim3(M_ / 128, D_ / 128), 256, 0, stream>>>(
        Cb, Wto, bo, bo, bo, out, out, out, 0);
}

// Round 2
// 475.561 us; speedup vs baseline: 1.0726x; 1.0038x over previous
//
#include <hip/hip_runtime.h>
#include <hip/hip_bf16.h>

#define B_  2
#define S_  2048
#define D_  1024
#define H_  16
#define HD_ 64
#define M_  (B_ * S_)   // 4096

typedef unsigned short u16;
typedef __attribute__((ext_vector_type(8))) short short8;
typedef __attribute__((ext_vector_type(4))) float f32x4;

#define MFMA16(a, b, c) __builtin_amdgcn_mfma_f32_16x16x32_bf16(a, b, c, 0, 0, 0)

__device__ __forceinline__ u16 f2bf(float f) {
    union { float f; unsigned u; } v; v.f = f;
    unsigned r = v.u + 0x7FFFu + ((v.u >> 16) & 1u);  // RNE
    return (u16)(r >> 16);
}

__device__ __forceinline__ void gl_lds16(const void* g, void* lds) {
    __builtin_amdgcn_global_load_lds(
        (const __attribute__((address_space(1))) unsigned int*)g,
        (__attribute__((address_space(3))) unsigned int*)lds, 16, 0, 0);
}

// ---------------------------------------------------------------------------
// Merged pre-pass: bid < 4096 -> X fp32->bf16; bid >= 4096 -> W transpose.
// ---------------------------------------------------------------------------
__global__ __launch_bounds__(256) void prepass(
    const float* __restrict__ X, u16* __restrict__ Xb,
    const float* __restrict__ w0, const float* __restrict__ w1,
    const float* __restrict__ w2, const float* __restrict__ w3,
    u16* __restrict__ t0, u16* __restrict__ t1,
    u16* __restrict__ t2, u16* __restrict__ t3) {
    const int bid = blockIdx.x;
    const int tid = threadIdx.x;
    if (bid < 4096) {
        const int i = (bid * 256 + tid) * 4;
        const float4 v = *(const float4*)(X + i);
        ushort4 o;
        o.x = f2bf(v.x); o.y = f2bf(v.y); o.z = f2bf(v.z); o.w = f2bf(v.w);
        *(ushort4*)(Xb + i) = o;
        return;
    }
    const int idx = bid - 4096;
    const int z = idx >> 10, rem = idx & 1023;
    const int kt = rem >> 5, nt = rem & 31;
    const float* W; u16* T;
    switch (z) {
        case 0: W = w0; T = t0; break;
        case 1: W = w1; T = t1; break;
        case 2: W = w2; T = t2; break;
        default: W = w3; T = t3; break;
    }
    __shared__ float t[32][33];
    const int r = tid >> 3, c4 = (tid & 7) * 4;
    const float4 v = *(const float4*)&W[(size_t)(kt * 32 + r) * D_ + nt * 32 + c4];
    t[c4 + 0][r] = v.x; t[c4 + 1][r] = v.y; t[c4 + 2][r] = v.z; t[c4 + 3][r] = v.w;
    __syncthreads();
    ushort4 o;
    o.x = f2bf(t[r][c4 + 0]); o.y = f2bf(t[r][c4 + 1]);
    o.z = f2bf(t[r][c4 + 2]); o.w = f2bf(t[r][c4 + 3]);
    *(ushort4*)&T[(size_t)(nt * 32 + r) * D_ + kt * 32 + c4] = o;
}

// ---------------------------------------------------------------------------
// bf16 MFMA GEMM, double-buffered single-barrier K-loop.
// C[M,N] = A[M,K] @ Bt[N,K]^T + bias. 128x128 tile, BK=32, 256 thr (2x2 waves).
// LDS K-loop: A0 | A1 | B0 | B1 (8 KB each) = 32 KB (within 36 KB block).
// mode 1 (fused QKV, grid.y=24): per-wave 64x64 tile staged in LDS
//   (stride 72 u16 -> 16B-aligned rows, 4-way max bank conflict), then
//   coalesced uint4 stores. sel 0/1 (Q,K): [B,H,S,HD] rows. sel 2 (V):
//   staged TRANSPOSED, written directly as VT [B,H,HD,S] (v_trans fused).
// mode 0: fp32 row-major [M,1024].
// ---------------------------------------------------------------------------
__global__ __launch_bounds__(256, 3) void gemm_bt_bf16(
    const u16* __restrict__ A, const u16* __restrict__ Bt,
    const float* __restrict__ bi0, const float* __restrict__ bi1, const float* __restrict__ bi2,
    void* __restrict__ o0, void* __restrict__ o1, void* __restrict__ o2,
    int mode) {
    __shared__ __align__(16) char smem[36864];

    const int tid = threadIdx.x;
    const int wave = tid >> 6, lane = tid & 63;
    const int quad = lane >> 4, l15 = lane & 15;
    const int wm = wave >> 1, wn = wave & 1;
    const int bm = blockIdx.x * 128, bn = blockIdx.y * 128;

    const int sel = bn >> 10;
    const float* bias = (sel == 0) ? bi0 : (sel == 1) ? bi1 : bi2;
    void* outp = (sel == 0) ? o0 : (sel == 1) ? o1 : o2;

    f32x4 acc[4][4];
#pragma unroll
    for (int i = 0; i < 4; ++i)
#pragma unroll
        for (int j = 0; j < 4; ++j) acc[i][j] = (f32x4)0.f;

    // chunk assignment for staging: c in 0..511, row=c>>2, e=c&3
    const int c0 = wave * 128 + lane;          // base chunk (i=0); i adds 64
    // prologue: stage k0=0 into buf0
#pragma unroll
    for (int i = 0; i < 2; ++i) {
        const int c = c0 + i * 64;
        const int row = c >> 2, e = c & 3;
        gl_lds16(A  + (size_t)(bm + row) * D_ + e * 8,
                 smem + (wave * 2 + i) * 1024);
        gl_lds16(Bt + (size_t)(bn + row) * D_ + e * 8,
                 smem + 16384 + (wave * 2 + i) * 1024);
    }
    __syncthreads();

    for (int it = 0; it < 32; ++it) {
        const int cur = it & 1;
        // stage next tile into the other buffer (DMA overlaps compute below)
        if (it < 31) {
            const int k0n = (it + 1) * 32;
            const int nb = cur ^ 1;
#pragma unroll
            for (int i = 0; i < 2; ++i) {
                const int c = c0 + i * 64;
                const int row = c >> 2, e = c & 3;
                gl_lds16(A  + (size_t)(bm + row) * D_ + k0n + e * 8,
                         smem + nb * 8192 + (wave * 2 + i) * 1024);
                gl_lds16(Bt + (size_t)(bn + row) * D_ + k0n + e * 8,
                         smem + 16384 + nb * 8192 + (wave * 2 + i) * 1024);
            }
        }

        short8 aF[4], bF[4];
#pragma unroll
        for (int mt = 0; mt < 4; ++mt)
            aF[mt] = *(const short8*)(smem + cur * 8192 +
                     ((wm * 64 + mt * 16 + l15) * 32 + quad * 8) * 2);
#pragma unroll
        for (int nt = 0; nt < 4; ++nt)
            bF[nt] = *(const short8*)(smem + 16384 + cur * 8192 +
                     ((wn * 64 + nt * 16 + l15) * 32 + quad * 8) * 2);
#pragma unroll
        for (int mt = 0; mt < 4; ++mt)
#pragma unroll
            for (int nt = 0; nt < 4; ++nt)
                acc[mt][nt] = MFMA16(aF[mt], bF[nt], acc[mt][nt]);

        __syncthreads();   // next-tile DMA complete + all waves done with cur
    }

    float bv[4];
#pragma unroll
    for (int nt = 0; nt < 4; ++nt)
        bv[nt] = bias[(bn & 1023) + wn * 64 + nt * 16 + l15];

    if (mode == 1) {
        // per-wave 64x64 bf16 tile in LDS (stride 72 u16 = 144 B, 16B aligned)
        u16* tw = (u16*)(smem + wave * 9216);
        if (sel < 2) {
#pragma unroll
            for (int mt = 0; mt < 4; ++mt)
#pragma unroll
                for (int nt = 0; nt < 4; ++nt)
#pragma unroll
                    for (int r = 0; r < 4; ++r)
                        tw[(mt * 16 + quad * 4 + r) * 72 + nt * 16 + l15] =
                            f2bf(acc[mt][nt][r] + bv[nt]);
        } else {
            // V: stage transposed -> tw[d][m]
#pragma unroll
            for (int mt = 0; mt < 4; ++mt)
#pragma unroll
                for (int nt = 0; nt < 4; ++nt)
#pragma unroll
                    for (int r = 0; r < 4; ++r)
                        tw[(nt * 16 + l15) * 72 + mt * 16 + quad * 4 + r] =
                            f2bf(acc[mt][nt][r] + bv[nt]);
        }
        // wave-private region: in-wave ds ordering suffices (no barrier)
        u16* ob = (u16*)outp;
        const int hh = ((bn & 1023) + wn * 64) >> 6;   // head 0..15
        const int rrow = lane >> 3, cc = (lane & 7) * 8;
        if (sel < 2) {
#pragma unroll
            for (int i = 0; i < 8; ++i) {
                const int row = i * 8 + rrow;
                const uint4 val = *(const uint4*)(tw + row * 72 + cc);
                const int m = bm + wm * 64 + row;
                const int bb = m >> 11, ss = m & (S_ - 1);
                *(uint4*)&ob[(((size_t)bb * H_ + hh) * S_ + ss) * HD_ + cc] = val;
            }
        } else {
            const int mbase = bm + wm * 64;            // 64-aligned, one batch
            const int bb = mbase >> 11;
            const int ss = (mbase & (S_ - 1)) + cc;
#pragma unroll
            for (int i = 0; i < 8; ++i) {
                const int row = i * 8 + rrow;          // d index
                const uint4 val = *(const uint4*)(tw + row * 72 + cc);
                *(uint4*)&ob[(((size_t)bb * H_ + hh) * HD_ + row) * S_ + ss] = val;
            }
        }
    } else {
        float* of = (float*)outp;
#pragma unroll
        for (int mt = 0; mt < 4; ++mt)
#pragma unroll
            for (int nt = 0; nt < 4; ++nt)
#pragma unroll
                for (int r = 0; r < 4; ++r) {
                    const int m = bm + wm * 64 + mt * 16 + quad * 4 + r;
                    const int n = bn + wn * 64 + nt * 16 + l15;
                    of[(size_t)m * D_ + n] = acc[mt][nt][r] + bv[nt];
                }
    }
}

// ---------------------------------------------------------------------------
// MFMA flash attention, TQ=64, both batches fused per block (pb read ONCE).
// Block = 256 thr (4 waves x 16 q-rows), grid = (S/64, H) = 512 blocks.
// LDS: 8K (Q_b0 -> Ps) | 4x8K K (buf x batch) | 4x8K V = 72 KB -> 2 blocks/CU
// (512 blocks = exactly one full dispatch wave at 2/CU).
// Q_b1 is staged into K slot (buf1,b1) and hoisted to registers before kt=0's
// prefetch DMA overwrites it (in-wave ds_read -> global_load_lds ordering).
// position_bias register loads are pipelined one full K-tile ahead to hide
// ~900-cyc HBM latency at the reduced occupancy (2 waves/SIMD).
// ---------------------------------------------------------------------------
#define PS_OFF   0        // Q(b0), reused as Ps after register hoist
#define AK2_OFF  8192     // + ((buf*2)+b)*8192, 4 slots
#define AV2_OFF  40960    // + ((buf*2)+b)*8192, 4 slots
#define Q1_STAGE 32768    // = K slot (buf1,b1): free until kt=0 prefetch

__global__ __launch_bounds__(256, 2) void attn_mfma(
    const u16* __restrict__ Qg, const u16* __restrict__ Kg, const u16* __restrict__ VTg,
    const float* __restrict__ pb, const float* __restrict__ mask,
    u16* __restrict__ Cb) {
    __shared__ __align__(16) char smem[73728];
    u16* PsU = (u16*)(smem + PS_OFF);

    const int tid = threadIdx.x;
    const int wave = tid >> 6, lane = tid & 63;
    const int quad = lane >> 4, l15 = lane & 15;

    const int qblk = blockIdx.x;
    const int h = blockIdx.y;
    const int q0 = qblk * 64;

    const u16* Qb0 = Qg  + (size_t)h        * (S_ * HD_);
    const u16* Qb1 = Qg  + (size_t)(H_ + h) * (S_ * HD_);
    const u16* Kb0 = Kg  + (size_t)h        * (S_ * HD_);
    const u16* Kb1 = Kg  + (size_t)(H_ + h) * (S_ * HD_);
    const u16* VT0 = VTg + (size_t)h        * (HD_ * S_);   // [HD][S]
    const u16* VT1 = VTg + (size_t)(H_ + h) * (HD_ * S_);

    // ---- prologue: stage Q(b0,b1) + K/V tile 0 (buf 0, both batches) ----
#pragma unroll
    for (int i = 0; i < 2; ++i) {
        const int c = (wave * 2 + i) * 64 + lane;  // 0..511
        const int row = c >> 3, e = c & 7, dc = e ^ (row & 7);
        const int off = (wave * 2 + i) * 1024;
        gl_lds16(Qb0 + (size_t)(q0 + row) * HD_ + dc * 8, smem + PS_OFF + off);
        gl_lds16(Qb1 + (size_t)(q0 + row) * HD_ + dc * 8, smem + Q1_STAGE + off);
        gl_lds16(Kb0 + (size_t)row * HD_ + dc * 8, smem + AK2_OFF + 0 * 8192 + off);
        gl_lds16(Kb1 + (size_t)row * HD_ + dc * 8, smem + AK2_OFF + 1 * 8192 + off);
        gl_lds16(VT0 + (size_t)row * S_ + dc * 8,  smem + AV2_OFF + 0 * 8192 + off);
        gl_lds16(VT1 + (size_t)row * S_ + dc * 8,  smem + AV2_OFF + 1 * 8192 + off);
    }
    __syncthreads();

    // hoist Q fragments for both batches (own-wave rows only)
    short8 aQ[2][2];
#pragma unroll
    for (int kc = 0; kc < 2; ++kc) {
        const int q = wave * 16 + l15;
        const int dc = kc * 4 + quad;
        const int boff = (q * 8 + (dc ^ (q & 7))) * 16;
        aQ[0][kc] = *(const short8*)(smem + PS_OFF + boff);
        aQ[1][kc] = *(const short8*)(smem + Q1_STAGE + boff);
    }

    // Ps addressing (kchunk-major): write base for this thread
    u16* Pw = PsU + (l15 >> 3) * 512 + (wave * 16 + quad * 4) * 8 + (l15 & 7);

    f32x4 O[2][4];
    float lst[2][4];
#pragma unroll
    for (int bb = 0; bb < 2; ++bb)
#pragma unroll
        for (int nt = 0; nt < 4; ++nt) { O[bb][nt] = (f32x4)0.f; lst[bb][nt] = 0.f; }

    // pipelined bias/mask registers for kt=0
    float pbc[4][4], mkc[2][4];
#pragma unroll
    for (int nt = 0; nt < 4; ++nt) {
        mkc[0][nt] = mask[nt * 16 + l15];
        mkc[1][nt] = mask[S_ + nt * 16 + l15];
    }
#pragma unroll
    for (int r = 0; r < 4; ++r) {
        const int qg = q0 + wave * 16 + quad * 4 + r;
        const float* rowp = pb + ((size_t)h * S_ + qg) * S_;
#pragma unroll
        for (int nt = 0; nt < 4; ++nt)
            pbc[r][nt] = __builtin_nontemporal_load(rowp + nt * 16 + l15);
    }

    for (int kt = 0; kt < S_ / 64; ++kt) {
        const int k0 = kt * 64;
        const int cur = kt & 1;
        float pbn[4][4], mkn[2][4];

        if (kt < S_ / 64 - 1) {
            const int nb = cur ^ 1;
            const int k0n = k0 + 64;
            // stage next K/V tiles (both batches) into the other buffer
#pragma unroll
            for (int i = 0; i < 2; ++i) {
                const int c = (wave * 2 + i) * 64 + lane;
                const int row = c >> 3, e = c & 7, dc = e ^ (row & 7);
                const int off = (wave * 2 + i) * 1024;
                gl_lds16(Kb0 + (size_t)(k0n + row) * HD_ + dc * 8,
                         smem + AK2_OFF + (nb * 2 + 0) * 8192 + off);
                gl_lds16(Kb1 + (size_t)(k0n + row) * HD_ + dc * 8,
                         smem + AK2_OFF + (nb * 2 + 1) * 8192 + off);
                gl_lds16(VT0 + (size_t)row * S_ + k0n + dc * 8,
                         smem + AV2_OFF + (nb * 2 + 0) * 8192 + off);
                gl_lds16(VT1 + (size_t)row * S_ + k0n + dc * 8,
                         smem + AV2_OFF + (nb * 2 + 1) * 8192 + off);
            }
            // next-tile bias/mask into registers (full kt of compute to hide)
#pragma unroll
            for (int nt = 0; nt < 4; ++nt) {
                mkn[0][nt] = mask[k0n + nt * 16 + l15];
                mkn[1][nt] = mask[S_ + k0n + nt * 16 + l15];
            }
#pragma unroll
            for (int r = 0; r < 4; ++r) {
                const int qg = q0 + wave * 16 + quad * 4 + r;
                const float* rowp = pb + ((size_t)h * S_ + qg) * S_ + k0n;
#pragma unroll
                for (int nt = 0; nt < 4; ++nt)
                    pbn[r][nt] = __builtin_nontemporal_load(rowp + nt * 16 + l15);
            }
        }

#pragma unroll
        for (int bb = 0; bb < 2; ++bb) {
            const int koff = AK2_OFF + (cur * 2 + bb) * 8192;
            const int voff = AV2_OFF + (cur * 2 + bb) * 8192;

            // ---- QK^T on buf[cur][bb] ----
            f32x4 sc[4];
#pragma unroll
            for (int nt = 0; nt < 4; ++nt) sc[nt] = (f32x4)0.f;
#pragma unroll
            for (int nt = 0; nt < 4; ++nt)
#pragma unroll
                for (int kc = 0; kc < 2; ++kc) {
                    const int kk = nt * 16 + l15;
                    const int dc = kc * 4 + quad;
                    const short8 bK = *(const short8*)(smem + koff +
                                       (kk * 8 + (dc ^ (kk & 7))) * 16);
                    sc[nt] = MFMA16(aQ[bb][kc], bK, sc[nt]);
                }

            // ---- no-max softmax: p = exp(s), per-lane partial row sums ----
#pragma unroll
            for (int r = 0; r < 4; ++r) {
                const float s0 = fmaf(sc[0][r], 0.125f, pbc[r][0] + mkc[bb][0]);
                const float s1 = fmaf(sc[1][r], 0.125f, pbc[r][1] + mkc[bb][1]);
                const float s2 = fmaf(sc[2][r], 0.125f, pbc[r][2] + mkc[bb][2]);
                const float s3 = fmaf(sc[3][r], 0.125f, pbc[r][3] + mkc[bb][3]);
                const float p0 = __expf(s0), p1 = __expf(s1);
                const float p2 = __expf(s2), p3 = __expf(s3);
                lst[bb][r] += (p0 + p1) + (p2 + p3);
                Pw[0 * 1024 + r * 8] = f2bf(p0);
                Pw[1 * 1024 + r * 8] = f2bf(p1);
                Pw[2 * 1024 + r * 8] = f2bf(p2);
                Pw[3 * 1024 + r * 8] = f2bf(p3);
            }

            // ---- PV on buf[cur][bb] (Ps is wave-private; in-wave DS order) ----
            short8 aP[2];
#pragma unroll
            for (int kc = 0; kc < 2; ++kc)
                aP[kc] = *(const short8*)(PsU + (kc * 4 + quad) * 512 +
                                          (wave * 16 + l15) * 8);
#pragma unroll
            for (int nt = 0; nt < 4; ++nt)
#pragma unroll
                for (int kc = 0; kc < 2; ++kc) {
                    const int d = nt * 16 + l15;
                    const int dc = kc * 4 + quad;
                    const short8 bV = *(const short8*)(smem + voff +
                                       (d * 8 + (dc ^ (d & 7))) * 16);
                    O[bb][nt] = MFMA16(aP[kc], bV, O[bb][nt]);
                }
        }

        if (kt < S_ / 64 - 1) {
#pragma unroll
            for (int r = 0; r < 4; ++r)
#pragma unroll
                for (int nt = 0; nt < 4; ++nt) pbc[r][nt] = pbn[r][nt];
#pragma unroll
            for (int nt = 0; nt < 4; ++nt) {
                mkc[0][nt] = mkn[0][nt]; mkc[1][nt] = mkn[1][nt];
            }
        }
        __syncthreads();   // next-tile DMA complete + all waves done with cur
    }

    // ---- epilogue: reduce l across the 16 col-lanes, write ctx bf16 ----
#pragma unroll
    for (int bb = 0; bb < 2; ++bb)
#pragma unroll
        for (int r = 0; r < 4; ++r) {
            float l = lst[bb][r];
#pragma unroll
            for (int off = 1; off < 16; off <<= 1)
                l += __shfl_xor(l, off, 64);
            const float inv = 1.f / l;
            const int s = q0 + wave * 16 + quad * 4 + r;
            u16* dst = Cb + ((size_t)bb * S_ + s) * D_ + h * HD_;
#pragma unroll
            for (int nt = 0; nt < 4; ++nt)
                dst[nt * 16 + l15] = f2bf(O[bb][nt][r] * inv);
        }
}

// ---------------------------------------------------------------------------
extern "C" void kernel_launch(void* const* d_in, const int* in_sizes, int n_in,
                              void* d_out, int out_size, void* d_ws, size_t ws_size,
                              hipStream_t stream) {
    const float* X    = (const float*)d_in[0];
    const float* mask = (const float*)d_in[1];
    const float* pb   = (const float*)d_in[2];
    const float* Wq   = (const float*)d_in[3];
    const float* bq   = (const float*)d_in[4];
    const float* Wk   = (const float*)d_in[5];
    const float* bk   = (const float*)d_in[6];
    const float* Wv   = (const float*)d_in[7];
    const float* bv   = (const float*)d_in[8];
    const float* Wo   = (const float*)d_in[9];
    const float* bo   = (const float*)d_in[10];
    float* out = (float*)d_out;

    // workspace (bf16 elems): 48 MB total
    u16* Xb    = (u16*)d_ws;                     // [4096,1024]       8 MB
    u16* WtQKV = Xb    + (size_t)M_ * D_;        // [3072,1024]       6 MB
    u16* Wto   = WtQKV + (size_t)3 * D_ * D_;    // [1024,1024]       2 MB
    u16* Qw    = Wto   + (size_t)D_ * D_;        // [B,H,S,HD]        8 MB
    u16* Kw    = Qw    + (size_t)M_ * D_;        //                   8 MB
    u16* VTw   = Kw    + (size_t)M_ * D_;        // [B,H,HD,S]        8 MB
    u16* Cb    = VTw   + (size_t)M_ * D_;        // [B,S,D]           8 MB

    // merged cvt + weight-transpose (one dispatch)
    prepass<<<8192, 256, 0, stream>>>(
        X, Xb, Wq, Wk, Wv, Wo,
        WtQKV, WtQKV + (size_t)D_ * D_, WtQKV + (size_t)2 * D_ * D_, Wto);

    // fused QKV: N = 3072; V written directly transposed (v_trans fused)
    gemm_bt_bf16<<<dim3(M_ / 128, 3 * D_ / 128), 256, 0, stream>>>(
        Xb, WtQKV, bq, bk, bv, Qw, Kw, VTw, 1);

    // both batches fused per block: pb panel read once
    attn_mfma<<<dim3(S_ / 64, H_), 256, 0, stream>>>(Qw, Kw, VTw, pb, mask, Cb);

    gemm_bt_bf16<<<dim3(M_ / 128, D_ / 128), 256, 0, stream>>>(
        Cb, Wto, bo, bo, bo, out, out, out, 0);
}